// Round 5
// baseline (13.402 us; speedup 1.0000x reference)
//
#include <hip/hip_runtime.h>
#include <hip/hip_bf16.h>

// SAXSMSAAttention collapses algebraically:
//   kv_x = layer_norm(saxs[...,None]) over a size-1 axis == ln_k_b (exact: x-mu==0)
//   => k[l,:], v[l,:] constant over l => softmax exactly uniform (1/512)
//   => o[b,q,:] = v_const (whole Q path cancels)
//   => out = msa + c,  c = (ln_k_b*Wv + bv) @ Wo + bo   (a 256-vector)
// Valid for any finite inputs; c computed on-device from the actual buffers.
//
// Fused single-kernel: each block redundantly computes c (identical bits in
// every block -> deterministic), overlapped with preloaded msa streaming
// reads. One dispatch. Nontemporal stores via native ext_vector float4
// (HIP_vector_type is a struct, rejected by the builtin).

#define D 256            // C_HID * N_HEADS == C_Q == 256
#define D4 (D / 4)       // 64 float4 columns
#define BLK 1024         // threads per block (16 waves)
#define NITER 4          // float4s per thread: 256 blk * 1024 thr * 4 = n4

typedef float f4 __attribute__((ext_vector_type(4)));

__global__ __launch_bounds__(BLK) void saxs_msa_fused(
        const float* __restrict__ msa,
        const float* __restrict__ ln_k_b,
        const float* __restrict__ Wv,
        const float* __restrict__ bv,
        const float* __restrict__ Wo,
        const float* __restrict__ bo,
        float* __restrict__ out,
        int n4) {
    const int t = threadIdx.x;
    const int gsize = gridDim.x * BLK;
    const int base = blockIdx.x * BLK + t;

    // ---- 1) issue streaming loads FIRST: HBM/L3 latency+BW overlaps prologue
    const f4* __restrict__ m4 = reinterpret_cast<const f4*>(msa);
    f4 m[NITER];
    const bool full = (base + (NITER - 1) * gsize) < n4;
    if (full) {
#pragma unroll
        for (int k = 0; k < NITER; ++k) m[k] = m4[base + k * gsize];
    } else {
#pragma unroll
        for (int k = 0; k < NITER; ++k)
            if (base + k * gsize < n4) m[k] = m4[base + k * gsize];
    }

    // ---- 2) prologue: c = (kb*Wv + bv) @ Wo + bo, float4 over columns.
    // rg (= wave id) is wave-uniform, so Wv/bv loads are broadcast, no LDS
    // staging needed.
    __shared__ f4 psum4[16 * D4];   // 16 row-groups x 64 f4-cols = 16 KB
    __shared__ f4 csf4[D4];

    {
        const int j4 = t & (D4 - 1);     // float4 column 0..63
        const int rg = t >> 6;           // row group 0..15 (wave-uniform)
        const float kb = ln_k_b[0];
        const f4* __restrict__ Wo4 = reinterpret_cast<const f4*>(Wo);
        f4 facc = (f4)(0.0f);
#pragma unroll
        for (int i = rg * 16; i < rg * 16 + 16; ++i) {
            const f4 w = Wo4[i * D4 + j4];
            const float vi = kb * Wv[i] + bv[i];   // wave-uniform broadcast
            facc += vi * w;
        }
        psum4[rg * D4 + j4] = facc;
    }
    __syncthreads();

    if (t < D4) {
        f4 cf = reinterpret_cast<const f4*>(bo)[t];
#pragma unroll
        for (int rg = 0; rg < 16; ++rg) {
            cf += psum4[rg * D4 + t];
        }
        csf4[t] = cf;
    }
    __syncthreads();

    // ---- 3) add & store (f4 index i has column i & 63; gsize % 64 == 0)
    const f4 cc = csf4[t & (D4 - 1)];
    f4* __restrict__ o4 = reinterpret_cast<f4*>(out);
    if (full) {
#pragma unroll
        for (int k = 0; k < NITER; ++k) {
            __builtin_nontemporal_store(m[k] + cc, &o4[base + k * gsize]);
        }
    } else {
#pragma unroll
        for (int k = 0; k < NITER; ++k) {
            if (base + k * gsize < n4) {
                __builtin_nontemporal_store(m[k] + cc, &o4[base + k * gsize]);
            }
        }
    }
}

extern "C" void kernel_launch(void* const* d_in, const int* in_sizes, int n_in,
                              void* d_out, int out_size, void* d_ws, size_t ws_size,
                              hipStream_t stream) {
    // setup_inputs order:
    // 0 msa, 1 saxs, 2 ln_q_w, 3 ln_q_b, 4 ln_k_w, 5 ln_k_b,
    // 6 Wq, 7 bq, 8 Wk, 9 bk, 10 Wv, 11 bv, 12 Wo, 13 bo
    const float* msa    = (const float*)d_in[0];
    const float* ln_k_b = (const float*)d_in[5];
    const float* Wv     = (const float*)d_in[10];
    const float* bv     = (const float*)d_in[11];
    const float* Wo     = (const float*)d_in[12];
    const float* bo     = (const float*)d_in[13];
    float* out = (float*)d_out;

    const int n4 = out_size / 4;                       // 1,048,576 float4s
    int grid = (n4 + BLK * NITER - 1) / (BLK * NITER); // = 256 exactly
    saxs_msa_fused<<<grid, BLK, 0, stream>>>(msa, ln_k_b, Wv, bv, Wo, bo, out, n4);
}